// Round 15
// baseline (312.811 us; speedup 1.0000x reference)
//
#include <hip/hip_runtime.h>
#include <utility>

// Problem constants: N=262144 rows, NX=NQ=64, NU=16, fp32.
#define NROWS 262144
#define BT 512                 // threads/block (8 waves)
#define RPB 256                // rows/block (= BT/4 quads * 2 rows each)

typedef float f16v __attribute__((ext_vector_type(16)));
typedef float f4v  __attribute__((ext_vector_type(4)));

// 16-float chunk as 4x f4v — lets the dense passes source 12 floats from
// LDS and 4 floats from global (ws) per chunk, splitting the m-stream
// across the LDS and VMEM return paths (r7/r10/r14 triangulation: the
// kernel sits at 94% of the LDS-return-bandwidth floor; VMEM is idle).
struct qch { f4v q[4]; };

// d_ws layout (floats) — two contiguous 9280-float phase blocks:
//  phase1 @0    : C1T[4096] | D11T[4096] | D12T[1024] | bv[64]
//  phase2 @9280 : AT [4096] | B1T [4096] | B2T [1024] | bx[64]
//  C1T[j*64+i]=C1[i][j]  D11T[i*64+k]=D11[k][i] (zeros at k<=i come from input)
//  D12T[j*64+i]=D12[i][j]  AT[j*64+k]=A[k][j]  B1T[i*64+k]=B1[k][i]
//  B2T[j*64+k]=B2[k][j]
// Fused kernel stages ONE 37.12 KB phase block at a time (overlay).
// Dense passes read quarters 0-2 of each chunk from LDS and quarter 3 from
// global ws (L1/L2-hot, identical data). D11 substitution stays all-LDS so
// global latency never enters the serial chain.

__global__ void prep_kernel(const float* __restrict__ A, const float* __restrict__ B1,
                            const float* __restrict__ B2, const float* __restrict__ C1,
                            const float* __restrict__ D11, const float* __restrict__ D12,
                            const float* __restrict__ bv, const float* __restrict__ bx,
                            float* __restrict__ ws) {
    int g = blockIdx.x * 256 + threadIdx.x;
    if (g < 4096) {
        int r = g >> 6, c = g & 63;       // source row r, col c (64x64 row-major)
        int to = c * 64 + r;
        ws[0     + to] = C1[g];           // C1T
        ws[4096  + to] = D11[g];          // D11T
        ws[9280  + to] = A[g];            // AT
        ws[13376 + to] = B1[g];           // B1T
    }
    if (g < 1024) {
        int r = g >> 4, c = g & 15;       // 64x16 row-major source
        int to = c * 64 + r;
        ws[8192  + to] = D12[g];          // D12T
        ws[17472 + to] = B2[g];           // B2T
    }
    if (g < 64) {
        ws[9216  + g] = bv[g];
        ws[18496 + g] = bx[g];
    }
}

__device__ __forceinline__ qch ldsq16(const float* p) {
    qch r;
    r.q[0] = *(const f4v*)(p);
    r.q[1] = *(const f4v*)(p + 4);
    r.q[2] = *(const f4v*)(p + 8);
    r.q[3] = *(const f4v*)(p + 12);
    return r;
}
// 12 floats from LDS + 4 from global: the dual-pipe chunk read.
__device__ __forceinline__ qch mix12_4(const float* lp, const float* gp) {
    qch r;
    r.q[0] = *(const f4v*)(lp);
    r.q[1] = *(const f4v*)(lp + 4);
    r.q[2] = *(const f4v*)(lp + 8);
    r.q[3] = *(const f4v*)(gp);
    return r;
}

// Pin pass boundaries (r6: +70 us): stops cross-pass live-range extension.
__device__ __forceinline__ void fence_sched() { __builtin_amdgcn_sched_barrier(0); }

// Quad-lane broadcast via DPP quad_perm:[Q,Q,Q,Q] — pure VALU (~2 cyc).
template<int Q>
__device__ __forceinline__ float qbcast(float v) {
    return __int_as_float(__builtin_amdgcn_update_dpp(
        0, __float_as_int(v), Q * 0x55, 0xF, 0xF, true));
}

// a.q[k] += m.q[k] * s (scalar splat) — compiler emits 16 v_fmac_f32
// (plain FMA: r14 proved v_pk_fma_f32 is cycle-neutral on gfx950).
__device__ __forceinline__ void fma4(qch& a, const qch& m, const float s) {
#pragma unroll
    for (int k = 0; k < 4; k++) a.q[k] += m.q[k] * s;
}

// Deferred relu (validated r14): D11's strict-lower zeros keep the owner's
// element at pre-activation through the whole substitution; one relu pass
// at the end yields exactly the post-activation w vector.
__device__ __forceinline__ void relu16(qch& a) {
#pragma unroll
    for (int k = 0; k < 4; k++)
#pragma unroll
        for (int e = 0; e < 4; e++) a.q[k][e] = fmaxf(a.q[k][e], 0.0f);
}

// Compile-time element access (static indexing, no scratch).
template<int E>
__device__ __forceinline__ float getel(const qch& a) { return a.q[E >> 2][E & 3]; }

// Substitution step I, two rows sharing the D11T column — ALL-LDS chunk
// (keeps global latency out of the serial broadcast->FMA chain).
template<int I>
__device__ __forceinline__ void substep2(qch& s0, qch& s1, const float* D11s, int c16) {
    const float w0 = fmaxf(qbcast<(I >> 4)>(getel<(I & 15)>(s0)), 0.0f);
    const float w1 = fmaxf(qbcast<(I >> 4)>(getel<(I & 15)>(s1)), 0.0f);
    const qch m = ldsq16(D11s + I * 64 + c16);
    fma4(s0, m, w0);
    fma4(s1, m, w1);
}
template<int... Is>
__device__ __forceinline__ void subst_all2(qch& s0, qch& s1, const float* D11s,
                                           int c16, std::integer_sequence<int, Is...>) {
    (substep2<Is>(s0, s1, D11s, c16), ...);
}

// 64-dim matvec, two rows: chunk = 12 LDS floats + 4 global floats; the
// multiplier scalars are quad-distributed and DPP-broadcast.
template<int J>
__device__ __forceinline__ void mv64step2(qch& a0, qch& a1, const float* Ml,
                                          const float* Mg, int c16,
                                          const qch& f0, const qch& f1) {
    const qch m = mix12_4(Ml + J * 64 + c16, Mg + J * 64 + c16 + 12);
    fma4(a0, m, qbcast<(J >> 4)>(getel<(J & 15)>(f0)));
    fma4(a1, m, qbcast<(J >> 4)>(getel<(J & 15)>(f1)));
}
template<int... Js>
__device__ __forceinline__ void mv64_2(qch& a0, qch& a1, const float* Ml,
                                       const float* Mg, int c16,
                                       const qch& f0, const qch& f1,
                                       std::integer_sequence<int, Js...>) {
    (mv64step2<Js>(a0, a1, Ml, Mg, c16, f0, f1), ...);
}

// 16-dim matvec, two rows (u fragments: 4 floats/lane/row), same split.
template<int J>
__device__ __forceinline__ void mv16step2(qch& a0, qch& a1, const float* Ml,
                                          const float* Mg, int c16,
                                          const f4v& f0, const f4v& f1) {
    const qch m = mix12_4(Ml + J * 64 + c16, Mg + J * 64 + c16 + 12);
    fma4(a0, m, qbcast<(J >> 2)>(f0[J & 3]));
    fma4(a1, m, qbcast<(J >> 2)>(f1[J & 3]));
}
template<int... Js>
__device__ __forceinline__ void mv16_2(qch& a0, qch& a1, const float* Ml,
                                       const float* Mg, int c16,
                                       const f4v& f0, const f4v& f1,
                                       std::integer_sequence<int, Js...>) {
    (mv16step2<Js>(a0, a1, Ml, Mg, c16, f0, f1), ...);
}

// Fused kernel: quad (4 lanes) per TWO rows (row q and row q+128); each lane
// owns a 16-output chunk of each. ONE phase table LDS-resident at a time
// (overlay): 37.12 KB. launch_bounds arg=3 (cap ~85 per measured model,
// 3 blocks/CU = 24 waves/CU): headroom for global-quarter prefetch without
// the 64-cap spill risk; r7 proved >=16 waves/CU suffices when LDS-bound.
// Pass order caps fragment liveness (round-7/10-proven schedule):
//   stage p1; 1. s = bv + C1 x + D12 u  [xf, uf die]
//   2. substitution s -> pre-act; deferred relu -> w
//   overlay p2 (live: s only)
//   3. acc = bx + B1 w                  [s dies]
//   4. reload x,u; acc += Ax + B2u
__global__ __launch_bounds__(BT, 3) void renl2_fused(const float* __restrict__ x,
                                                     const float* __restrict__ u,
                                                     const float* __restrict__ ws,
                                                     float* __restrict__ out) {
    __shared__ __align__(64) float sm[9280];    // 37.12 KB
    const int tid = threadIdx.x;
    const int c16 = (tid & 3) << 4;       // quad chunk offset
    const size_t row0 = (size_t)blockIdx.x * RPB;   // rows [row0, row0+256)

    // ---- per-lane x/u fragments for both rows (fully coalesced) ----
    const qch xf0 = ldsq16(x + row0 * 64 + (size_t)tid * 16);
    const qch xf1 = ldsq16(x + (row0 + 128) * 64 + (size_t)tid * 16);
    const f4v uf0 = *(const f4v*)(u + row0 * 16 + (size_t)tid * 4);
    const f4v uf1 = *(const f4v*)(u + (row0 + 128) * 16 + (size_t)tid * 4);

    // ---- stage phase-1 table (2320 float4) ----
    const float4* wsv = (const float4*)ws;
    float4* smv = (float4*)sm;
#pragma unroll
    for (int i = 0; i < 4; i++) smv[tid + i * BT] = wsv[tid + i * BT];
    if (tid < 2320 - 4 * BT) smv[tid + 4 * BT] = wsv[tid + 4 * BT];
    __syncthreads();

    // ---- pass 1: s = bv + C1 x + D12 u   (xf, uf die here) ----
    qch s0 = ldsq16(sm + 9216 + c16);
    qch s1 = s0;
    mv64_2(s0, s1, sm + 0,    ws + 0,    c16, xf0, xf1,
           std::make_integer_sequence<int, 64>{});
    mv16_2(s0, s1, sm + 8192, ws + 8192, c16, uf0, uf1,
           std::make_integer_sequence<int, 16>{});
    fence_sched();

    // ---- pass 2: substitution (all-LDS) + deferred relu (s -> w) ----
    subst_all2(s0, s1, sm + 4096, c16, std::make_integer_sequence<int, 64>{});
    relu16(s0);
    relu16(s1);
    fence_sched();

    // ---- overlay: phase-2 table (live regs: s only) ----
    __syncthreads();
#pragma unroll
    for (int i = 0; i < 4; i++) smv[tid + i * BT] = wsv[2320 + tid + i * BT];
    if (tid < 2320 - 4 * BT) smv[tid + 4 * BT] = wsv[2320 + tid + 4 * BT];
    __syncthreads();
    // local layout now: AT@0 | B1T@4096 | B2T@8192 | bx@9216
    // global (ws) absolute: AT@9280 | B1T@13376 | B2T@17472

    // ---- pass 3: acc = bx + B1 w   (s dies here) ----
    qch acc0 = ldsq16(sm + 9216 + c16);
    qch acc1 = acc0;
    mv64_2(acc0, acc1, sm + 4096, ws + 13376, c16, s0, s1,
           std::make_integer_sequence<int, 64>{});
    fence_sched();

    // ---- pass 4: reload x/u (L3-hot; laundered so pass-1 loads can't be
    //      CSE-forwarded and resurrect their live ranges), acc += Ax + B2u ----
    size_t r0 = row0;
    asm volatile("" : "+s"(r0));          // opaque: forces a true reload
    const qch xg0 = ldsq16(x + r0 * 64 + (size_t)tid * 16);
    const qch xg1 = ldsq16(x + (r0 + 128) * 64 + (size_t)tid * 16);
    const f4v ug0 = *(const f4v*)(u + r0 * 16 + (size_t)tid * 4);
    const f4v ug1 = *(const f4v*)(u + (r0 + 128) * 16 + (size_t)tid * 4);
    mv64_2(acc0, acc1, sm + 0,    ws + 9280,  c16, xg0, xg1,
           std::make_integer_sequence<int, 64>{});
    mv16_2(acc0, acc1, sm + 8192, ws + 17472, c16, ug0, ug1,
           std::make_integer_sequence<int, 16>{});

    // ---- two 64B stores: x_dot for both rows ----
    const size_t q = (size_t)(tid >> 2);
    *(f16v*)(out + (row0 + q) * 64 + c16)       = __builtin_bit_cast(f16v, acc0);
    *(f16v*)(out + (row0 + 128 + q) * 64 + c16) = __builtin_bit_cast(f16v, acc1);
}

extern "C" void kernel_launch(void* const* d_in, const int* in_sizes, int n_in,
                              void* d_out, int out_size, void* d_ws, size_t ws_size,
                              hipStream_t stream) {
    const float* x   = (const float*)d_in[0];
    const float* u   = (const float*)d_in[1];
    const float* A   = (const float*)d_in[2];
    const float* B1  = (const float*)d_in[3];
    const float* B2  = (const float*)d_in[4];
    const float* C1  = (const float*)d_in[5];
    const float* D11 = (const float*)d_in[6];
    const float* D12 = (const float*)d_in[7];
    const float* bv  = (const float*)d_in[8];
    const float* bx  = (const float*)d_in[9];
    float* out = (float*)d_out;
    float* ws  = (float*)d_ws;

    prep_kernel<<<16, 256, 0, stream>>>(A, B1, B2, C1, D11, D12, bv, bx, ws);
    renl2_fused<<<NROWS / RPB, BT, 0, stream>>>(x, u, ws, out);
}